// Round 2
// baseline (731.720 us; speedup 1.0000x reference)
//
#include <hip/hip_runtime.h>
#include <math.h>

#define NPTS  65536
#define NG    64
#define NP    16
#define NLAY  20

// ---------------------------------------------------------------------------
// Phase A: POCA. One thread per (polygon g, point n).
// x_tmp/x_old [16] live in registers; simplex projection via 16-elem
// descending bitonic network (all indices compile-time after unroll).
// Writes points[g][n] as float2 into d_ws (coalesced).
// ---------------------------------------------------------------------------
__global__ __launch_bounds__(256) void poca_kernel(
    const float* __restrict__ y, const float* __restrict__ W,
    const float* __restrict__ step_p, const int* __restrict__ polys,
    float2* __restrict__ pts)
{
    const int g = blockIdx.y;
    const int n = blockIdx.x * 256 + threadIdx.x;
    const float step = step_p[0];

    // A_g columns (broadcast loads: whole block shares g)
    float a0[NP], a1[NP];
#pragma unroll
    for (int p = 0; p < NP; ++p) {
        const int idx = polys[g * NP + p];
        a0[p] = W[idx * 2 + 0];
        a1[p] = W[idx * 2 + 1];
    }

    const float y0 = y[2 * n + 0];
    const float y1 = y[2 * n + 1];

    float xt[NP], xo[NP];
#pragma unroll
    for (int p = 0; p < NP; ++p) { xt[p] = 0.f; xo[p] = 0.f; }

    for (int layer = 0; layer < NLAY; ++layer) {
        // Q = y - x_tmp @ A   (finite by construction; nan_to_num is identity)
        float q0 = y0, q1 = y1;
#pragma unroll
        for (int p = 0; p < NP; ++p) {
            q0 = fmaf(-xt[p], a0[p], q0);
            q1 = fmaf(-xt[p], a1[p], q1);
        }
        // x = x_tmp - grad*step = x_tmp + step * (Q @ A^T)
        float x[NP], u[NP];
#pragma unroll
        for (int p = 0; p < NP; ++p) {
            const float d = fmaf(q0, a0[p], q1 * a1[p]);
            x[p] = fmaf(step, d, xt[p]);
            u[p] = x[p];
        }
        // descending bitonic sort of u[16] — branch-free, fully unrolled
#pragma unroll
        for (int k = 2; k <= NP; k <<= 1) {
#pragma unroll
            for (int j = k >> 1; j > 0; j >>= 1) {
#pragma unroll
                for (int i = 0; i < NP; ++i) {
                    const int l = i ^ j;
                    if (l > i) {
                        const bool up = ((i & k) == 0);   // compile-time
                        const float mx = fmaxf(u[i], u[l]);
                        const float mn = fminf(u[i], u[l]);
                        u[i] = up ? mx : mn;
                        u[l] = up ? mn : mx;
                    }
                }
            }
        }
        // tau = v[k] at last index where u_j > v_j (prefix-true property)
        float cs = u[0];
        float tau = cs - 1.0f;
#pragma unroll
        for (int j = 1; j < NP; ++j) {
            cs += u[j];
            const float vv = (cs - 1.0f) * (1.0f / (float)(j + 1));
            tau = (u[j] > vv) ? vv : tau;
        }
        // x_new = relu(x - tau); Nesterov momentum
        const float c = (float)layer / ((float)layer + 3.0f);
#pragma unroll
        for (int p = 0; p < NP; ++p) {
            const float xn = fmaxf(x[p] - tau, 0.f);
            xt[p] = fmaf(c, xn - xo[p], xn);
            xo[p] = xn;
        }
    }

    // points = x_new @ A
    float p0 = 0.f, p1 = 0.f;
#pragma unroll
    for (int p = 0; p < NP; ++p) {
        p0 = fmaf(xo[p], a0[p], p0);
        p1 = fmaf(xo[p], a1[p], p1);
    }
    pts[(size_t)g * NPTS + n] = make_float2(p0, p1);
}

// ---------------------------------------------------------------------------
// Phase B: f-iteration over 65-element rows + fused yhat/f/f0 epilogue.
// One thread per point n. Simplex projection via Michelot's exact
// active-set fixpoint (no sort needed; identical result up to fp rounding).
// ---------------------------------------------------------------------------
__global__ __launch_bounds__(256) void fiter_kernel(
    const float* __restrict__ y, const float* __restrict__ step_p,
    const float2* __restrict__ pts, float* __restrict__ out)
{
    const int n = blockIdx.x * 256 + threadIdx.x;
    const float step = step_p[0];
    const float y0 = y[2 * n + 0];
    const float y1 = y[2 * n + 1];

    // gs = grad * step, grad = [1, dist_0..dist_63]; dist from points
    float gs[NG + 1];
    gs[0] = step;
#pragma unroll
    for (int g = 0; g < NG; ++g) {
        const float2 p = pts[(size_t)g * NPTS + n];
        const float dx = y0 - p.x;
        const float dy = y1 - p.y;
        gs[1 + g] = sqrtf(dx * dx + dy * dy) * step;
    }

    float x[NG + 1], fo[NG + 1];   // x doubles as f_tmp storage
#pragma unroll
    for (int i = 0; i <= NG; ++i) { x[i] = 0.f; fo[i] = 0.f; }

    for (int layer = 0; layer < NLAY; ++layer) {
        // x = f_tmp - grad*step ; track full sum (4-way split chains)
        float s0 = 0.f, s1 = 0.f, s2 = 0.f, s3 = 0.f;
#pragma unroll
        for (int i = 0; i <= NG; ++i) {
            x[i] -= gs[i];
            if ((i & 3) == 0)      s0 += x[i];
            else if ((i & 3) == 1) s1 += x[i];
            else if ((i & 3) == 2) s2 += x[i];
            else                   s3 += x[i];
        }
        float tau = ((s0 + s1) + (s2 + s3) - 1.0f) * (1.0f / 65.0f);
        int kprev = NG + 1;
        for (int pass = 0; pass < NG + 1; ++pass) {
            float t0 = 0.f, t1 = 0.f, t2 = 0.f, t3 = 0.f;
            int cnt = 0;
#pragma unroll
            for (int i = 0; i <= NG; ++i) {
                const bool in = x[i] > tau;
                const float xv = in ? x[i] : 0.f;
                if ((i & 3) == 0)      t0 += xv;
                else if ((i & 3) == 1) t1 += xv;
                else if ((i & 3) == 2) t2 += xv;
                else                   t3 += xv;
                cnt += in ? 1 : 0;
            }
            if (cnt == kprev) break;     // active set stable -> tau final
            kprev = cnt;
            tau = (((t0 + t1) + (t2 + t3)) - 1.0f) / (float)cnt;
        }
        const float c = (float)layer / ((float)layer + 3.0f);
#pragma unroll
        for (int i = 0; i <= NG; ++i) {
            const float fn = fmaxf(x[i] - tau, 0.f);
            x[i] = fmaf(c, fn - fo[i], fn);
            fo[i] = fn;
        }
    }

    // yhat = y*f0 + sum_g f_g * points[g]
    float acc0 = y0 * fo[0];
    float acc1 = y1 * fo[0];
#pragma unroll
    for (int g = 0; g < NG; ++g) {
        const float2 p = pts[(size_t)g * NPTS + n];
        acc0 = fmaf(fo[1 + g], p.x, acc0);
        acc1 = fmaf(fo[1 + g], p.y, acc1);
    }

    // outputs: yhat [N,2] | f [N,64] | f0 [N]
    ((float2*)out)[n] = make_float2(acc0, acc1);
    float4* fsec = (float4*)(out + 2 * (size_t)NPTS);
#pragma unroll
    for (int g4 = 0; g4 < NG / 4; ++g4) {
        fsec[(size_t)n * (NG / 4) + g4] = make_float4(
            fo[1 + 4 * g4], fo[2 + 4 * g4], fo[3 + 4 * g4], fo[4 + 4 * g4]);
    }
    out[2 * (size_t)NPTS + (size_t)NPTS * NG + n] = fo[0];
}

// ---------------------------------------------------------------------------
extern "C" void kernel_launch(void* const* d_in, const int* in_sizes, int n_in,
                              void* d_out, int out_size, void* d_ws, size_t ws_size,
                              hipStream_t stream) {
    const float* y      = (const float*)d_in[0];
    const float* W      = (const float*)d_in[1];
    const float* step   = (const float*)d_in[2];
    const int*   polys  = (const int*)d_in[3];
    float*       out    = (float*)d_out;
    float2*      pts    = (float2*)d_ws;   // 64*65536*8B = 32 MB scratch

    dim3 gridA(NPTS / 256, NG);
    poca_kernel<<<gridA, 256, 0, stream>>>(y, W, step, polys, pts);
    fiter_kernel<<<NPTS / 256, 256, 0, stream>>>(y, step, pts, out);
}